// Round 7
// baseline (128.451 us; speedup 1.0000x reference)
//
#include <hip/hip_runtime.h>

// LikelihoodRatioEstimator: N=8192, D=128 fp32 inputs, 8 fp32 scalar outputs.
//
// d2[i][j] = ||x_i||^2 + ||y_j||^2 - 2 x_i.y_j ; u = 1 + d2  (u >= ~80 always)
//   B = log(mean_offdiag(1/u));  mean_neg = -mean_offdiag(ln u) - B
//   mean_sig_neg = mean_offdiag(1/(1 + c*u)), c = exp(B)
//   pos path: diagonal only, exact fp32 (prep).
//
// R6 (verified absmax 0.0): single gram pass; per-block cc = mean_tile(1/u)
// for the sigmoid sum (sensitivity <=0.25 per unit ln c, tol 0.11); diag
// blocks report their diag sigmoid terms for exact subtraction in fin.
//
// R7: occupancy + issue-count attack on the gram epilogue (was 52% VALUBusy,
// 2 waves/SIMD, 47us):
//  - A-tile no longer staged in LDS: LDS = B-only 32.9 KB -> 4 blocks/CU =
//    4 waves/SIMD. Consecutive bids share tr -> the CU's 4 blocks read the
//    same 32 KB A-tile -> L1-resident. (Not R2's failure: B stays in LDS,
//    occupancy doubles instead of dropping.)
//  - log-product: one log2 per 8-elem product (u<=600 -> prod8 <= 1.7e22,
//    fits float). 3 -> 2.125 transcendentals/elem.
//  - phase A stores u back into acc (same liveness) -> phase B skips the
//    u-recompute; staging loop halves (B only).

#define N_ROWS 8192
#define DDIM 128
#define NBLK 4096           // (8192/128)^2
#define NN1 67100672.0      // 8192 * 8191
#define LN2 0.6931471805599453
#define TILE_INV (1.0f / 16384.0f)

typedef __bf16 bf16x8 __attribute__((ext_vector_type(8)));
typedef float f32x4 __attribute__((ext_vector_type(4)));

__device__ __forceinline__ unsigned short f32_to_bf16(float f) {
  unsigned int u = __float_as_uint(f);
  u += 0x7FFFu + ((u >> 16) & 1u);   // RNE
  return (unsigned short)(u >> 16);
}

// ---------------------------------------------------------------------------
// prep: fp32 -> bf16, row norms (exact fp32), diagonal logits.
__global__ __launch_bounds__(256) void prep_kernel(
    const float* __restrict__ x, const float* __restrict__ y,
    unsigned short* __restrict__ xb, unsigned short* __restrict__ yb,
    float* __restrict__ x2, float* __restrict__ y2, float* __restrict__ posl) {
  int tid = threadIdx.x;
  int wave = tid >> 6, lane = tid & 63;
  int r = blockIdx.x * 4 + wave;
  float2 xv = ((const float2*)(x + (size_t)r * DDIM))[lane];
  float2 yv = ((const float2*)(y + (size_t)r * DDIM))[lane];

  unsigned int px = (unsigned int)f32_to_bf16(xv.x) |
                    ((unsigned int)f32_to_bf16(xv.y) << 16);
  unsigned int py = (unsigned int)f32_to_bf16(yv.x) |
                    ((unsigned int)f32_to_bf16(yv.y) << 16);
  ((unsigned int*)xb)[(size_t)r * (DDIM / 2) + lane] = px;
  ((unsigned int*)yb)[(size_t)r * (DDIM / 2) + lane] = py;

  float xx = fmaf(xv.x, xv.x, xv.y * xv.y);
  float yy = fmaf(yv.x, yv.x, yv.y * yv.y);
  float xy = fmaf(xv.x, yv.x, xv.y * yv.y);
  #pragma unroll
  for (int o = 32; o; o >>= 1) {
    xx += __shfl_xor(xx, o);
    yy += __shfl_xor(yy, o);
    xy += __shfl_xor(xy, o);
  }
  if (lane == 0) {
    x2[r] = xx;
    y2[r] = yy;
    float d2 = fmaxf(xx + yy - 2.0f * xy, 0.0f);
    posl[r] = -__logf(1.0f + d2);
  }
}

// ---------------------------------------------------------------------------
// gram: 128x128 tile/block, 4 waves (2x2), 4x4 MFMA 16x16x32 frags.
// B-tile in XOR-swizzled LDS (2-way-free b128); A-frags direct from global
// (L1/L2-resident; same tr across the CU's resident blocks). Two-phase
// epilogue: A: s0=sum 1/u (rcp), s1=sum log2 via 8-elem products; u stored
// back into acc. Block-reduce s0 -> cc. B: sW = sum 1/(1+cc*u).
__global__ __launch_bounds__(256, 2) void gram_kernel(
    const unsigned short* __restrict__ xb, const unsigned short* __restrict__ yb,
    const float* __restrict__ x2, const float* __restrict__ y2,
    float* __restrict__ parts0, float* __restrict__ parts1,
    float* __restrict__ partsW, float* __restrict__ partsD) {
  __shared__ uint4 Bsm[2048];   // 32 KB (B tile only)
  __shared__ float red[16];

  int tid = threadIdx.x, bid = blockIdx.x;
  int tr = bid >> 6, tc = bid & 63;
  int wave = tid >> 6, lane = tid & 63;
  int wr = wave >> 1, wc = wave & 1;
  int quad = lane >> 4, m = lane & 15;

  const uint4* Bg = (const uint4*)yb + (size_t)tc * 2048;
  #pragma unroll
  for (int it = 0; it < 8; ++it) {
    int cid = it * 256 + tid;
    int row = cid >> 4, c = cid & 15;
    Bsm[row * 16 + (c ^ (row & 15))] = Bg[cid];
  }
  __syncthreads();

  const bf16x8* A8 = (const bf16x8*)xb;   // global, unswizzled
  const bf16x8* B8 = (const bf16x8*)Bsm;  // LDS, swizzled
  size_t abase = ((size_t)(tr * 128 + wr * 64 + m)) * 16 + quad;
  int brow0 = wc * 64 + m;

  f32x4 acc[4][4];
  #pragma unroll
  for (int i = 0; i < 4; ++i)
    #pragma unroll
    for (int j = 0; j < 4; ++j)
      acc[i][j] = (f32x4){0.f, 0.f, 0.f, 0.f};

  #pragma unroll
  for (int ks = 0; ks < 4; ++ks) {
    int ch = (ks * 4 + quad) ^ m;
    bf16x8 af[4], bfr[4];
    #pragma unroll
    for (int f = 0; f < 4; ++f) {
      af[f]  = A8[abase + f * 256 + ks * 4];          // f*16 rows = f*256 chunks
      bfr[f] = B8[(brow0 + f * 16) * 16 + ch];
    }
    #pragma unroll
    for (int fi = 0; fi < 4; ++fi)
      #pragma unroll
      for (int fj = 0; fj < 4; ++fj)
        acc[fi][fj] = __builtin_amdgcn_mfma_f32_16x16x32_bf16(
            af[fi], bfr[fj], acc[fi][fj], 0, 0, 0);
  }

  // C/D layout: col = lane&15, row = quad*4 + reg. u >= ~80 -> no clamp.
  float x2v1[16], y2v[4];
  #pragma unroll
  for (int fi = 0; fi < 4; ++fi)
    #pragma unroll
    for (int r = 0; r < 4; ++r)
      x2v1[fi * 4 + r] =
          x2[tr * 128 + wr * 64 + fi * 16 + quad * 4 + r] + 1.0f;
  #pragma unroll
  for (int fj = 0; fj < 4; ++fj)
    y2v[fj] = y2[tc * 128 + wc * 64 + fj * 16 + m];

  // ---- phase A: 1/u (rcp) + log2 via 8-elem products; store u into acc ----
  float s0a = 0.f, s0b = 0.f, s1a = 0.f, s1b = 0.f;
  #pragma unroll
  for (int fi = 0; fi < 4; ++fi) {
    float p0, p1;
    #pragma unroll
    for (int fj = 0; fj < 4; ++fj) {
      #pragma unroll
      for (int r = 0; r < 4; ++r) {
        float u = fmaf(-2.0f, acc[fi][fj][r], x2v1[fi * 4 + r] + y2v[fj]);
        acc[fi][fj][r] = u;                      // keep for phase B
        float e = __builtin_amdgcn_rcpf(u);
        if (r & 1) s0a += e; else s0b += e;
        if (fj < 2) p0 = (fj == 0 && r == 0) ? u : p0 * u;
        else        p1 = (fj == 2 && r == 0) ? u : p1 * u;
      }
    }
    s1a += __builtin_amdgcn_logf(p0);            // log2(prod of 8 u's)
    s1b += __builtin_amdgcn_logf(p1);
  }
  float s0 = s0a + s0b, s1 = s1a + s1b;
  #pragma unroll
  for (int o = 32; o; o >>= 1) {
    s0 += __shfl_xor(s0, o);
    s1 += __shfl_xor(s1, o);
  }
  if (lane == 0) { red[wave] = s0; red[4 + wave] = s1; }
  __syncthreads();
  float cc = (red[0] + red[1] + red[2] + red[3]) * TILE_INV;  // block-local c

  // ---- phase B: 1/(1+cc*u) from stored u; diag blocks collect diag terms --
  float sWa = 0.f, sWb = 0.f, sD = 0.f;
  if (tr != tc) {
    #pragma unroll
    for (int fi = 0; fi < 4; ++fi)
      #pragma unroll
      for (int fj = 0; fj < 4; ++fj)
        #pragma unroll
        for (int r = 0; r < 4; ++r) {
          float sg = __builtin_amdgcn_rcpf(fmaf(cc, acc[fi][fj][r], 1.0f));
          if (r & 1) sWa += sg; else sWb += sg;
        }
  } else {
    #pragma unroll
    for (int fi = 0; fi < 4; ++fi)
      #pragma unroll
      for (int fj = 0; fj < 4; ++fj)
        #pragma unroll
        for (int r = 0; r < 4; ++r) {
          float sg = __builtin_amdgcn_rcpf(fmaf(cc, acc[fi][fj][r], 1.0f));
          if (r & 1) sWa += sg; else sWb += sg;
          int lr = wr * 64 + fi * 16 + quad * 4 + r;
          int lc = wc * 64 + fj * 16 + m;
          sD += (lr == lc) ? sg : 0.0f;
        }
  }
  float sW = sWa + sWb;
  #pragma unroll
  for (int o = 32; o; o >>= 1) sW += __shfl_xor(sW, o);
  if (tr == tc) {
    #pragma unroll
    for (int o = 32; o; o >>= 1) sD += __shfl_xor(sD, o);
    if (lane == 0) red[12 + wave] = sD;
  }
  if (lane == 0) red[8 + wave] = sW;
  __syncthreads();
  if (tid == 0) {
    parts0[bid] = red[0] + red[1] + red[2] + red[3];
    parts1[bid] = red[4] + red[5] + red[6] + red[7];
    partsW[bid] = red[8] + red[9] + red[10] + red[11];
    if (tr == tc) partsD[tr] = red[12] + red[13] + red[14] + red[15];
  }
}

// ---------------------------------------------------------------------------
// 4-wide packed double block reduction (one barrier tree for 4 sums).
__device__ __forceinline__ void block_reduce4_d(double* v, double* buf) {
  int tid = threadIdx.x;
  #pragma unroll
  for (int k = 0; k < 4; ++k) buf[k * 256 + tid] = v[k];
  __syncthreads();
  #pragma unroll
  for (int s = 128; s > 0; s >>= 1) {
    if (tid < s) {
      #pragma unroll
      for (int k = 0; k < 4; ++k) buf[k * 256 + tid] += buf[k * 256 + tid + s];
    }
    __syncthreads();
  }
  #pragma unroll
  for (int k = 0; k < 4; ++k) v[k] = buf[k * 256];
  __syncthreads();
}

// fin: all 8 outputs; double accumulation, float transcendentals.
__global__ __launch_bounds__(256) void fin_kernel(
    const float* __restrict__ parts0, const float* __restrict__ parts1,
    const float* __restrict__ partsW, const float* __restrict__ partsD,
    const float* __restrict__ posl, float* __restrict__ out8) {
  __shared__ double dbuf[1024];
  int tid = threadIdx.x;

  double v[4] = {0.0, 0.0, 0.0, 0.0};
  for (int i = tid; i < NBLK; i += 256) {
    v[0] += (double)parts0[i];   // sum_all 1/u
    v[1] += (double)parts1[i];   // sum_all log2(u)
    v[2] += (double)partsW[i];   // sum_all 1/(1+cc_b*u)
  }
  if (tid < 64) v[3] = (double)partsD[tid];   // diag sigmoid terms
  block_reduce4_d(v, dbuf);
  double sum0 = v[0], sum1 = v[1], sumW = v[2], sumD = v[3];

  double w[4] = {0.0, 0.0, 0.0, 0.0};
  for (int i = tid; i < N_ROWS; i += 256) {
    float p = posl[i];
    w[0] += (double)p;
    w[1] += (double)__expf(p);   // diag 1/u (posl exact fp32)
  }
  block_reduce4_d(w, dbuf);
  double sumP = w[0], sumE = w[1];

  double me = (sum0 - sumE) / NN1;   // exact mean_offdiag 1/u
  float cf = (float)me;
  double z[4] = {0.0, 0.0, 0.0, 0.0};
  for (int i = tid; i < N_ROWS; i += 256) {
    float p = posl[i];
    float uii = __expf(-p);                       // 1 + d2_ii
    z[0] += (double)(1.0f / fmaf(cf, uii, 1.0f)); // sigmoid(pos_i), exact c
  }
  block_reduce4_d(z, dbuf);
  double sumSig = z[0];

  if (tid == 0) {
    double B = log(me);
    double mean_pos = sumP / (double)N_ROWS - B;
    double attraction = -mean_pos;
    double repulsion = me * exp(-B);                   // ~1.0
    double mean_neg = -(LN2 * sum1 + sumP) / NN1 - B;
    out8[0] = (float)(attraction + repulsion);
    out8[1] = (float)mean_pos;
    out8[2] = (float)mean_neg;
    out8[3] = (float)(sumSig / (double)N_ROWS);
    out8[4] = (float)((sumW - sumD) / NN1);
    out8[5] = (float)attraction;
    out8[6] = (float)repulsion;
    out8[7] = (float)B;
  }
}

// ---------------------------------------------------------------------------
extern "C" void kernel_launch(void* const* d_in, const int* in_sizes, int n_in,
                              void* d_out, int out_size, void* d_ws, size_t ws_size,
                              hipStream_t stream) {
  const float* x = (const float*)d_in[0];  // context_embedding
  const float* y = (const float*)d_in[1];  // target_embedding

  char* ws = (char*)d_ws;
  unsigned short* xb = (unsigned short*)ws;
  unsigned short* yb = (unsigned short*)(ws + (size_t)2 * 1024 * 1024);
  float* x2     = (float*)(ws + (size_t)4 * 1024 * 1024);
  float* y2     = x2 + N_ROWS;
  float* posl   = y2 + N_ROWS;
  float* parts0 = posl + N_ROWS;
  float* parts1 = parts0 + NBLK;
  float* partsW = parts1 + NBLK;
  float* partsD = partsW + NBLK;

  hipLaunchKernelGGL(prep_kernel, dim3(2048), dim3(256), 0, stream,
                     x, y, xb, yb, x2, y2, posl);
  hipLaunchKernelGGL(gram_kernel, dim3(NBLK), dim3(256), 0, stream,
                     xb, yb, x2, y2, parts0, parts1, partsW, partsD);
  hipLaunchKernelGGL(fin_kernel, dim3(1), dim3(256), 0, stream,
                     parts0, parts1, partsW, partsD, posl, (float*)d_out);
}

// Round 9
// 123.631 us; speedup vs baseline: 1.0390x; 1.0390x over previous
//
#include <hip/hip_runtime.h>

// LikelihoodRatioEstimator: N=8192, D=128 fp32 inputs, 8 fp32 scalar outputs.
//
// d2[i][j] = ||x_i||^2 + ||y_j||^2 - 2 x_i.y_j ; u = 1 + d2  (u in [~80,~600])
//   B = log(mean_offdiag(1/u));  mean_neg = -mean_offdiag(ln u) - B
//   mean_sig_neg = mean_offdiag(1/(1 + c*u)), c = exp(B)
//   pos path: diagonal only, exact fp32 (prep).
//
// Single gram pass (R6, absmax 0.0): per-block cc = mean_tile(1/u) for the
// sigmoid sum; diag blocks report their diag sigmoid terms for exact
// subtraction in fin; exact c for everything else from full sum(1/u).
//
// R9: R8 (4 simultaneous changes) produced NaN in the log sum; un-bisectable
// by inspection -> rebuild on the PROVEN R6 base with exactly ONE change:
// 512-thread / 8-wave blocks (2x4 wave grid, 4x2 frags = R3's verified
// mapping). LDS 64.5KB caps at 2 blocks/CU either way, so this doubles
// resident waves: 16 waves/CU = 4 waves/SIMD vs R6's 2. Epilogue stays R6's
// per-element rcp+log (no rcp-combine, no log-products). red[] has 32
// dedicated slots, zero reuse. fin/prep are byte-level R6 (proven).

#define N_ROWS 8192
#define DDIM 128
#define NBLK 4096           // (8192/128)^2
#define NN1 67100672.0      // 8192 * 8191
#define LN2 0.6931471805599453
#define TILE_INV (1.0f / 16384.0f)

typedef __bf16 bf16x8 __attribute__((ext_vector_type(8)));
typedef float f32x4 __attribute__((ext_vector_type(4)));

__device__ __forceinline__ unsigned short f32_to_bf16(float f) {
  unsigned int u = __float_as_uint(f);
  u += 0x7FFFu + ((u >> 16) & 1u);   // RNE
  return (unsigned short)(u >> 16);
}

// ---------------------------------------------------------------------------
// prep: fp32 -> bf16, row norms (exact fp32), diagonal logits.  (R6, proven)
__global__ __launch_bounds__(256) void prep_kernel(
    const float* __restrict__ x, const float* __restrict__ y,
    unsigned short* __restrict__ xb, unsigned short* __restrict__ yb,
    float* __restrict__ x2, float* __restrict__ y2, float* __restrict__ posl) {
  int tid = threadIdx.x;
  int wave = tid >> 6, lane = tid & 63;
  int r = blockIdx.x * 4 + wave;
  float2 xv = ((const float2*)(x + (size_t)r * DDIM))[lane];
  float2 yv = ((const float2*)(y + (size_t)r * DDIM))[lane];

  unsigned int px = (unsigned int)f32_to_bf16(xv.x) |
                    ((unsigned int)f32_to_bf16(xv.y) << 16);
  unsigned int py = (unsigned int)f32_to_bf16(yv.x) |
                    ((unsigned int)f32_to_bf16(yv.y) << 16);
  ((unsigned int*)xb)[(size_t)r * (DDIM / 2) + lane] = px;
  ((unsigned int*)yb)[(size_t)r * (DDIM / 2) + lane] = py;

  float xx = fmaf(xv.x, xv.x, xv.y * xv.y);
  float yy = fmaf(yv.x, yv.x, yv.y * yv.y);
  float xy = fmaf(xv.x, yv.x, xv.y * yv.y);
  #pragma unroll
  for (int o = 32; o; o >>= 1) {
    xx += __shfl_xor(xx, o);
    yy += __shfl_xor(yy, o);
    xy += __shfl_xor(xy, o);
  }
  if (lane == 0) {
    x2[r] = xx;
    y2[r] = yy;
    float d2 = fmaxf(xx + yy - 2.0f * xy, 0.0f);
    posl[r] = -__logf(1.0f + d2);
  }
}

// ---------------------------------------------------------------------------
// gram: 128x128 tile/block, 8 waves (2x4; 64x32 wave tiles), 4x2 MFMA frags
// (R3-verified mapping). A+B in XOR-swizzled LDS (2-way-free b128). R6's
// two-phase per-element epilogue: A: s0=sum 1/u, s1=sum log2(u), u stored
// into acc; block-reduce s0 -> cc. B: sW=sum 1/(1+cc*u); diag blocks also
// collect their diag sigmoid terms (sD).
__global__ __launch_bounds__(512, 2) void gram_kernel(
    const unsigned short* __restrict__ xb, const unsigned short* __restrict__ yb,
    const float* __restrict__ x2, const float* __restrict__ y2,
    float* __restrict__ parts0, float* __restrict__ parts1,
    float* __restrict__ partsW, float* __restrict__ partsD) {
  __shared__ uint4 Asm[2048];   // 32 KB
  __shared__ uint4 Bsm[2048];   // 32 KB
  __shared__ float red[32];     // [0:8) s0, [8:16) s1, [16:24) sW, [24:32) sD

  int tid = threadIdx.x, bid = blockIdx.x;
  int tr = bid >> 6, tc = bid & 63;
  int wave = tid >> 6, lane = tid & 63;
  int wr = wave >> 2, wc = wave & 3;
  int quad = lane >> 4, m = lane & 15;

  const uint4* Ag = (const uint4*)xb + (size_t)tr * 2048;
  const uint4* Bg = (const uint4*)yb + (size_t)tc * 2048;
  #pragma unroll
  for (int it = 0; it < 4; ++it) {
    int cid = it * 512 + tid;
    int row = cid >> 4, c = cid & 15;
    int sw = row * 16 + (c ^ (row & 15));
    Asm[sw] = Ag[cid];
    Bsm[sw] = Bg[cid];
  }
  __syncthreads();

  const bf16x8* A8 = (const bf16x8*)Asm;
  const bf16x8* B8 = (const bf16x8*)Bsm;
  int arow = wr * 64 + m;
  int brow = wc * 32 + m;

  f32x4 acc[4][2];
  #pragma unroll
  for (int i = 0; i < 4; ++i)
    #pragma unroll
    for (int j = 0; j < 2; ++j)
      acc[i][j] = (f32x4){0.f, 0.f, 0.f, 0.f};

  #pragma unroll
  for (int ks = 0; ks < 4; ++ks) {
    int ch = (ks * 4 + quad) ^ m;
    bf16x8 af[4], bfv[2];
    #pragma unroll
    for (int f = 0; f < 4; ++f) af[f] = A8[(arow + f * 16) * 16 + ch];
    #pragma unroll
    for (int f = 0; f < 2; ++f) bfv[f] = B8[(brow + f * 16) * 16 + ch];
    #pragma unroll
    for (int fi = 0; fi < 4; ++fi)
      #pragma unroll
      for (int fj = 0; fj < 2; ++fj)
        acc[fi][fj] = __builtin_amdgcn_mfma_f32_16x16x32_bf16(
            af[fi], bfv[fj], acc[fi][fj], 0, 0, 0);
  }

  // C/D layout: col = lane&15, row = quad*4 + reg. u >= ~80 -> no clamp.
  float x2v1[16], y2v[2];
  #pragma unroll
  for (int fi = 0; fi < 4; ++fi)
    #pragma unroll
    for (int r = 0; r < 4; ++r)
      x2v1[fi * 4 + r] =
          x2[tr * 128 + wr * 64 + fi * 16 + quad * 4 + r] + 1.0f;
  #pragma unroll
  for (int fj = 0; fj < 2; ++fj)
    y2v[fj] = y2[tc * 128 + wc * 32 + fj * 16 + m];

  // ---- phase A (R6 per-element): 1/u and log2(u); store u into acc ----
  float s0a = 0.f, s0b = 0.f, s1a = 0.f, s1b = 0.f;
  #pragma unroll
  for (int fi = 0; fi < 4; ++fi) {
    #pragma unroll
    for (int fj = 0; fj < 2; ++fj) {
      #pragma unroll
      for (int r = 0; r < 4; ++r) {
        float u = fmaf(-2.0f, acc[fi][fj][r], x2v1[fi * 4 + r] + y2v[fj]);
        acc[fi][fj][r] = u;                      // keep for phase B
        float e = __builtin_amdgcn_rcpf(u);
        float lg = __builtin_amdgcn_logf(u);     // log2; x ln2 in finalizer
        if (r & 1) { s0a += e; s1a += lg; } else { s0b += e; s1b += lg; }
      }
    }
  }
  float s0 = s0a + s0b, s1 = s1a + s1b;
  #pragma unroll
  for (int o = 32; o; o >>= 1) {
    s0 += __shfl_xor(s0, o);
    s1 += __shfl_xor(s1, o);
  }
  if (lane == 0) { red[wave] = s0; red[8 + wave] = s1; }
  __syncthreads();
  float cc = 0.0f;
  #pragma unroll
  for (int w = 0; w < 8; ++w) cc += red[w];
  cc *= TILE_INV;                                // block-local mean(1/u)

  // ---- phase B (R6 per-element): 1/(1+cc*u) from stored u ----
  float sWa = 0.f, sWb = 0.f, sD = 0.f;
  bool isdiag = (tr == tc);
  if (!isdiag) {
    #pragma unroll
    for (int fi = 0; fi < 4; ++fi)
      #pragma unroll
      for (int fj = 0; fj < 2; ++fj)
        #pragma unroll
        for (int r = 0; r < 4; ++r) {
          float sg = __builtin_amdgcn_rcpf(fmaf(cc, acc[fi][fj][r], 1.0f));
          if (r & 1) sWa += sg; else sWb += sg;
        }
  } else {
    #pragma unroll
    for (int fi = 0; fi < 4; ++fi)
      #pragma unroll
      for (int fj = 0; fj < 2; ++fj)
        #pragma unroll
        for (int r = 0; r < 4; ++r) {
          float sg = __builtin_amdgcn_rcpf(fmaf(cc, acc[fi][fj][r], 1.0f));
          if (r & 1) sWa += sg; else sWb += sg;
          int lr = wr * 64 + fi * 16 + quad * 4 + r;
          int lc = wc * 32 + fj * 16 + m;
          sD += (lr == lc) ? sg : 0.0f;
        }
  }
  float sW = sWa + sWb;
  #pragma unroll
  for (int o = 32; o; o >>= 1) sW += __shfl_xor(sW, o);
  if (isdiag) {
    #pragma unroll
    for (int o = 32; o; o >>= 1) sD += __shfl_xor(sD, o);
    if (lane == 0) red[24 + wave] = sD;
  }
  if (lane == 0) red[16 + wave] = sW;
  __syncthreads();
  if (tid == 0) {
    float t0 = 0.f, t1 = 0.f, tW = 0.f;
    #pragma unroll
    for (int w = 0; w < 8; ++w) {
      t0 += red[w];
      t1 += red[8 + w];
      tW += red[16 + w];
    }
    parts0[bid] = t0;
    parts1[bid] = t1;
    partsW[bid] = tW;
    if (isdiag) {
      float tD = 0.f;
      #pragma unroll
      for (int w = 0; w < 8; ++w) tD += red[24 + w];
      partsD[tr] = tD;
    }
  }
}

// ---------------------------------------------------------------------------
// 4-wide packed double block reduction (one barrier tree for 4 sums). (R6)
__device__ __forceinline__ void block_reduce4_d(double* v, double* buf) {
  int tid = threadIdx.x;
  #pragma unroll
  for (int k = 0; k < 4; ++k) buf[k * 256 + tid] = v[k];
  __syncthreads();
  #pragma unroll
  for (int s = 128; s > 0; s >>= 1) {
    if (tid < s) {
      #pragma unroll
      for (int k = 0; k < 4; ++k) buf[k * 256 + tid] += buf[k * 256 + tid + s];
    }
    __syncthreads();
  }
  #pragma unroll
  for (int k = 0; k < 4; ++k) v[k] = buf[k * 256];
  __syncthreads();
}

// fin: all 8 outputs; double accumulation, float transcendentals. (R6, proven)
__global__ __launch_bounds__(256) void fin_kernel(
    const float* __restrict__ parts0, const float* __restrict__ parts1,
    const float* __restrict__ partsW, const float* __restrict__ partsD,
    const float* __restrict__ posl, float* __restrict__ out8) {
  __shared__ double dbuf[1024];
  int tid = threadIdx.x;

  double v[4] = {0.0, 0.0, 0.0, 0.0};
  for (int i = tid; i < NBLK; i += 256) {
    v[0] += (double)parts0[i];   // sum_all 1/u
    v[1] += (double)parts1[i];   // sum_all log2(u)
    v[2] += (double)partsW[i];   // sum_all 1/(1+cc_b*u)
  }
  if (tid < 64) v[3] = (double)partsD[tid];   // diag sigmoid terms
  block_reduce4_d(v, dbuf);
  double sum0 = v[0], sum1 = v[1], sumW = v[2], sumD = v[3];

  double w[4] = {0.0, 0.0, 0.0, 0.0};
  for (int i = tid; i < N_ROWS; i += 256) {
    float p = posl[i];
    w[0] += (double)p;
    w[1] += (double)__expf(p);   // diag 1/u (posl exact fp32)
  }
  block_reduce4_d(w, dbuf);
  double sumP = w[0], sumE = w[1];

  double me = (sum0 - sumE) / NN1;   // exact mean_offdiag 1/u
  float cf = (float)me;
  double z[4] = {0.0, 0.0, 0.0, 0.0};
  for (int i = tid; i < N_ROWS; i += 256) {
    float p = posl[i];
    float uii = __expf(-p);                       // 1 + d2_ii
    z[0] += (double)(1.0f / fmaf(cf, uii, 1.0f)); // sigmoid(pos_i), exact c
  }
  block_reduce4_d(z, dbuf);
  double sumSig = z[0];

  if (tid == 0) {
    double B = log(me);
    double mean_pos = sumP / (double)N_ROWS - B;
    double attraction = -mean_pos;
    double repulsion = me * exp(-B);                   // ~1.0
    double mean_neg = -(LN2 * sum1 + sumP) / NN1 - B;
    out8[0] = (float)(attraction + repulsion);
    out8[1] = (float)mean_pos;
    out8[2] = (float)mean_neg;
    out8[3] = (float)(sumSig / (double)N_ROWS);
    out8[4] = (float)((sumW - sumD) / NN1);
    out8[5] = (float)attraction;
    out8[6] = (float)repulsion;
    out8[7] = (float)B;
  }
}

// ---------------------------------------------------------------------------
extern "C" void kernel_launch(void* const* d_in, const int* in_sizes, int n_in,
                              void* d_out, int out_size, void* d_ws, size_t ws_size,
                              hipStream_t stream) {
  const float* x = (const float*)d_in[0];  // context_embedding
  const float* y = (const float*)d_in[1];  // target_embedding

  char* ws = (char*)d_ws;
  unsigned short* xb = (unsigned short*)ws;
  unsigned short* yb = (unsigned short*)(ws + (size_t)2 * 1024 * 1024);
  float* x2     = (float*)(ws + (size_t)4 * 1024 * 1024);
  float* y2     = x2 + N_ROWS;
  float* posl   = y2 + N_ROWS;
  float* parts0 = posl + N_ROWS;
  float* parts1 = parts0 + NBLK;
  float* partsW = parts1 + NBLK;
  float* partsD = partsW + NBLK;

  hipLaunchKernelGGL(prep_kernel, dim3(2048), dim3(256), 0, stream,
                     x, y, xb, yb, x2, y2, posl);
  hipLaunchKernelGGL(gram_kernel, dim3(NBLK), dim3(512), 0, stream,
                     xb, yb, x2, y2, parts0, parts1, partsW, partsD);
  hipLaunchKernelGGL(fin_kernel, dim3(1), dim3(256), 0, stream,
                     parts0, parts1, partsW, partsD, posl, (float*)d_out);
}

// Round 10
// 113.738 us; speedup vs baseline: 1.1294x; 1.0870x over previous
//
#include <hip/hip_runtime.h>

// LikelihoodRatioEstimator: N=8192, D=128 fp32 inputs, 8 fp32 scalar outputs.
//
// d2[i][j] = ||x_i||^2 + ||y_j||^2 - 2 x_i.y_j ; u = 1 + d2  (u in [~80,~500])
//   B = log(mean_offdiag(1/u));  mean_neg = -mean_offdiag(ln u) - B
//   mean_sig_neg = mean_offdiag(1/(1 + c*u)), c = exp(B)
//   pos path: diagonal only, exact fp32 (prep).
//
// Single gram pass: per-block cc = mean_tile(1/u) for the sigmoid sum (R6,
// absmax 0.0); diag blocks report their diag sigmoid terms for exact
// subtraction in fin; exact c for everything else from full sum(1/u).
//
// R10 = R9 (512-thr/8-wave gram, absmax 0.0) + the R8 epilogue optimizations
// with R8's bug fixed (R8 left p1 UNINITIALIZED because its fj<2 test was
// never false in the 4x2 frag grid -> NaN):
//  - 4-way rcp-combine: 1/u0+..+1/u3 = rP*P23*(u0+u1) + rP*P01*(u2+u3) with
//    ONE v_rcp (rP=rcp(P01*P23)); same for sigmoid terms v=1+cc*u.
//  - one log2 per 8-elem product (u<=500 -> prod8 <= 2e21, fits fp32).
//    Transcendental issue: 96 -> 20 per lane.
//  - prep writes per-block partials of sum(posl), sum(1/(1+d2)) (plain
//    stores, no atomics) -> fin drops its two 8192-elem exp loops.

#define N_ROWS 8192
#define DDIM 128
#define NBLK 4096           // (8192/128)^2
#define NPREP 2048
#define NN1 67100672.0      // 8192 * 8191
#define LN2 0.6931471805599453
#define TILE_INV (1.0f / 16384.0f)

typedef __bf16 bf16x8 __attribute__((ext_vector_type(8)));
typedef float f32x4 __attribute__((ext_vector_type(4)));

__device__ __forceinline__ unsigned short f32_to_bf16(float f) {
  unsigned int u = __float_as_uint(f);
  u += 0x7FFFu + ((u >> 16) & 1u);   // RNE
  return (unsigned short)(u >> 16);
}

// ---------------------------------------------------------------------------
// prep: fp32 -> bf16, row norms (exact fp32), diagonal logits, and per-block
// partials of sum(posl) / sum(1/(1+d2_ii)) so fin skips its posl exp loops.
__global__ __launch_bounds__(256) void prep_kernel(
    const float* __restrict__ x, const float* __restrict__ y,
    unsigned short* __restrict__ xb, unsigned short* __restrict__ yb,
    float* __restrict__ x2, float* __restrict__ y2, float* __restrict__ posl,
    float* __restrict__ preP, float* __restrict__ preE) {
  __shared__ float erP[4], erE[4];
  int tid = threadIdx.x;
  int wave = tid >> 6, lane = tid & 63;
  int r = blockIdx.x * 4 + wave;
  float2 xv = ((const float2*)(x + (size_t)r * DDIM))[lane];
  float2 yv = ((const float2*)(y + (size_t)r * DDIM))[lane];

  unsigned int px = (unsigned int)f32_to_bf16(xv.x) |
                    ((unsigned int)f32_to_bf16(xv.y) << 16);
  unsigned int py = (unsigned int)f32_to_bf16(yv.x) |
                    ((unsigned int)f32_to_bf16(yv.y) << 16);
  ((unsigned int*)xb)[(size_t)r * (DDIM / 2) + lane] = px;
  ((unsigned int*)yb)[(size_t)r * (DDIM / 2) + lane] = py;

  float xx = fmaf(xv.x, xv.x, xv.y * xv.y);
  float yy = fmaf(yv.x, yv.x, yv.y * yv.y);
  float xy = fmaf(xv.x, yv.x, xv.y * yv.y);
  #pragma unroll
  for (int o = 32; o; o >>= 1) {
    xx += __shfl_xor(xx, o);
    yy += __shfl_xor(yy, o);
    xy += __shfl_xor(xy, o);
  }
  if (lane == 0) {
    x2[r] = xx;
    y2[r] = yy;
    float d2 = fmaxf(xx + yy - 2.0f * xy, 0.0f);
    float pl = -__logf(1.0f + d2);
    posl[r] = pl;
    erP[wave] = pl;
    erE[wave] = 1.0f / (1.0f + d2);
  }
  __syncthreads();
  if (tid == 0) {
    preP[blockIdx.x] = erP[0] + erP[1] + erP[2] + erP[3];
    preE[blockIdx.x] = erE[0] + erE[1] + erE[2] + erE[3];
  }
}

// ---------------------------------------------------------------------------
// gram: 128x128 tile/block, 8 waves (2x4; 64x32 wave tiles), 4x2 MFMA frags,
// A+B in XOR-swizzled LDS (2-way-free b128). Two-phase epilogue with 4-way
// rcp-combine and per-8 log-products; u stored into acc between phases.
__global__ __launch_bounds__(512, 2) void gram_kernel(
    const unsigned short* __restrict__ xb, const unsigned short* __restrict__ yb,
    const float* __restrict__ x2, const float* __restrict__ y2,
    float* __restrict__ parts0, float* __restrict__ parts1,
    float* __restrict__ partsW, float* __restrict__ partsD) {
  __shared__ uint4 Asm[2048];   // 32 KB
  __shared__ uint4 Bsm[2048];   // 32 KB
  __shared__ float red[32];     // [0:8) s0, [8:16) s1, [16:24) sW, [24:32) sD

  int tid = threadIdx.x, bid = blockIdx.x;
  int tr = bid >> 6, tc = bid & 63;
  int wave = tid >> 6, lane = tid & 63;
  int wr = wave >> 2, wc = wave & 3;
  int quad = lane >> 4, m = lane & 15;

  const uint4* Ag = (const uint4*)xb + (size_t)tr * 2048;
  const uint4* Bg = (const uint4*)yb + (size_t)tc * 2048;
  #pragma unroll
  for (int it = 0; it < 4; ++it) {
    int cid = it * 512 + tid;
    int row = cid >> 4, c = cid & 15;
    int sw = row * 16 + (c ^ (row & 15));
    Asm[sw] = Ag[cid];
    Bsm[sw] = Bg[cid];
  }
  __syncthreads();

  const bf16x8* A8 = (const bf16x8*)Asm;
  const bf16x8* B8 = (const bf16x8*)Bsm;
  int arow = wr * 64 + m;
  int brow = wc * 32 + m;

  f32x4 acc[4][2];
  #pragma unroll
  for (int i = 0; i < 4; ++i)
    #pragma unroll
    for (int j = 0; j < 2; ++j)
      acc[i][j] = (f32x4){0.f, 0.f, 0.f, 0.f};

  #pragma unroll
  for (int ks = 0; ks < 4; ++ks) {
    int ch = (ks * 4 + quad) ^ m;
    bf16x8 af[4], bfv[2];
    #pragma unroll
    for (int f = 0; f < 4; ++f) af[f] = A8[(arow + f * 16) * 16 + ch];
    #pragma unroll
    for (int f = 0; f < 2; ++f) bfv[f] = B8[(brow + f * 16) * 16 + ch];
    #pragma unroll
    for (int fi = 0; fi < 4; ++fi)
      #pragma unroll
      for (int fj = 0; fj < 2; ++fj)
        acc[fi][fj] = __builtin_amdgcn_mfma_f32_16x16x32_bf16(
            af[fi], bfv[fj], acc[fi][fj], 0, 0, 0);
  }

  // C/D layout: col = lane&15, row = quad*4 + reg. u >= ~80 -> no clamp.
  float x2v1[16], y2v[2];
  #pragma unroll
  for (int fi = 0; fi < 4; ++fi)
    #pragma unroll
    for (int r = 0; r < 4; ++r)
      x2v1[fi * 4 + r] =
          x2[tr * 128 + wr * 64 + fi * 16 + quad * 4 + r] + 1.0f;
  #pragma unroll
  for (int fj = 0; fj < 2; ++fj)
    y2v[fj] = y2[tc * 128 + wc * 32 + fj * 16 + m];

  // ---- phase A: sum 1/u via 4-way rcp-combine; one log2 per 8-elem prod.
  //      1/u0+..+1/u3 = rP*P23*(u0+u1) + rP*P01*(u2+u3),
  //      P01=u0u1, P23=u2u3, rP=rcp(P01*P23). u stored back into acc.
  float s0a = 0.f, s0b = 0.f, s1 = 0.f;
  #pragma unroll
  for (int fi = 0; fi < 4; ++fi) {
    float pl;
    #pragma unroll
    for (int fj = 0; fj < 2; ++fj) {
      float u0 = fmaf(-2.0f, acc[fi][fj][0], x2v1[fi * 4 + 0] + y2v[fj]);
      float u1 = fmaf(-2.0f, acc[fi][fj][1], x2v1[fi * 4 + 1] + y2v[fj]);
      float u2 = fmaf(-2.0f, acc[fi][fj][2], x2v1[fi * 4 + 2] + y2v[fj]);
      float u3 = fmaf(-2.0f, acc[fi][fj][3], x2v1[fi * 4 + 3] + y2v[fj]);
      acc[fi][fj][0] = u0; acc[fi][fj][1] = u1;
      acc[fi][fj][2] = u2; acc[fi][fj][3] = u3;
      float P01 = u0 * u1, P23 = u2 * u3, P = P01 * P23;
      float rP = __builtin_amdgcn_rcpf(P);
      s0a = fmaf(rP * P23, u0 + u1, s0a);
      s0b = fmaf(rP * P01, u2 + u3, s0b);
      pl = (fj == 0) ? P : pl * P;      // fj unrolled: pl init'd at fj==0
    }
    s1 += __builtin_amdgcn_logf(pl);    // log2(prod of 8 u's <= ~2e21)
  }
  float s0 = s0a + s0b;
  #pragma unroll
  for (int o = 32; o; o >>= 1) {
    s0 += __shfl_xor(s0, o);
    s1 += __shfl_xor(s1, o);
  }
  if (lane == 0) { red[wave] = s0; red[8 + wave] = s1; }
  __syncthreads();
  float cc = 0.0f;
  #pragma unroll
  for (int w = 0; w < 8; ++w) cc += red[w];
  cc *= TILE_INV;                                // block-local mean(1/u)

  // ---- phase B: sum 1/(1+cc*u) via 4-way rcp-combine on v = 1+cc*u ----
  float sWa = 0.f, sWb = 0.f, sD = 0.f;
  bool isdiag = (tr == tc);
  if (!isdiag) {
    #pragma unroll
    for (int fi = 0; fi < 4; ++fi) {
      #pragma unroll
      for (int fj = 0; fj < 2; ++fj) {
        float v0 = fmaf(cc, acc[fi][fj][0], 1.0f);
        float v1 = fmaf(cc, acc[fi][fj][1], 1.0f);
        float v2 = fmaf(cc, acc[fi][fj][2], 1.0f);
        float v3 = fmaf(cc, acc[fi][fj][3], 1.0f);
        float Q01 = v0 * v1, Q23 = v2 * v3, Q = Q01 * Q23;
        float rQ = __builtin_amdgcn_rcpf(Q);
        sWa = fmaf(rQ * Q23, v0 + v1, sWa);
        sWb = fmaf(rQ * Q01, v2 + v3, sWb);
      }
    }
  } else {
    // 64 of 4096 blocks: per-element path (R9-proven) to get diag terms.
    #pragma unroll
    for (int fi = 0; fi < 4; ++fi)
      #pragma unroll
      for (int fj = 0; fj < 2; ++fj)
        #pragma unroll
        for (int r = 0; r < 4; ++r) {
          float sg = __builtin_amdgcn_rcpf(fmaf(cc, acc[fi][fj][r], 1.0f));
          if (r & 1) sWa += sg; else sWb += sg;
          int lr = wr * 64 + fi * 16 + quad * 4 + r;
          int lc = wc * 32 + fj * 16 + m;
          sD += (lr == lc) ? sg : 0.0f;
        }
  }
  float sW = sWa + sWb;
  #pragma unroll
  for (int o = 32; o; o >>= 1) sW += __shfl_xor(sW, o);
  if (isdiag) {
    #pragma unroll
    for (int o = 32; o; o >>= 1) sD += __shfl_xor(sD, o);
    if (lane == 0) red[24 + wave] = sD;
  }
  if (lane == 0) red[16 + wave] = sW;
  __syncthreads();
  if (tid == 0) {
    float t0 = 0.f, t1 = 0.f, tW = 0.f;
    #pragma unroll
    for (int w = 0; w < 8; ++w) {
      t0 += red[w];
      t1 += red[8 + w];
      tW += red[16 + w];
    }
    parts0[bid] = t0;
    parts1[bid] = t1;
    partsW[bid] = tW;
    if (isdiag) {
      float tD = 0.f;
      #pragma unroll
      for (int w = 0; w < 8; ++w) tD += red[24 + w];
      partsD[tr] = tD;
    }
  }
}

// ---------------------------------------------------------------------------
// 4-wide packed double block reduction (one barrier tree for 4 sums).
__device__ __forceinline__ void block_reduce4_d(double* v, double* buf) {
  int tid = threadIdx.x;
  #pragma unroll
  for (int k = 0; k < 4; ++k) buf[k * 256 + tid] = v[k];
  __syncthreads();
  #pragma unroll
  for (int s = 128; s > 0; s >>= 1) {
    if (tid < s) {
      #pragma unroll
      for (int k = 0; k < 4; ++k) buf[k * 256 + tid] += buf[k * 256 + tid + s];
    }
    __syncthreads();
  }
  #pragma unroll
  for (int k = 0; k < 4; ++k) v[k] = buf[k * 256];
  __syncthreads();
}

// fin: all 8 outputs; double accumulation, float transcendentals.
__global__ __launch_bounds__(256) void fin_kernel(
    const float* __restrict__ parts0, const float* __restrict__ parts1,
    const float* __restrict__ partsW, const float* __restrict__ partsD,
    const float* __restrict__ preP, const float* __restrict__ preE,
    const float* __restrict__ posl, float* __restrict__ out8) {
  __shared__ double dbuf[1024];
  int tid = threadIdx.x;

  double v[4] = {0.0, 0.0, 0.0, 0.0};
  #pragma unroll
  for (int it = 0; it < 4; ++it) {         // 4096 floats = 1024 float4
    int i = it * 256 + tid;
    float4 q0 = ((const float4*)parts0)[i];
    float4 q1 = ((const float4*)parts1)[i];
    float4 qW = ((const float4*)partsW)[i];
    v[0] += (double)q0.x + (double)q0.y + (double)q0.z + (double)q0.w;
    v[1] += (double)q1.x + (double)q1.y + (double)q1.z + (double)q1.w;
    v[2] += (double)qW.x + (double)qW.y + (double)qW.z + (double)qW.w;
  }
  if (tid < 64) v[3] = (double)partsD[tid];   // diag sigmoid terms
  block_reduce4_d(v, dbuf);
  double sum0 = v[0], sum1 = v[1], sumW = v[2], sumD = v[3];

  double w[4] = {0.0, 0.0, 0.0, 0.0};
  #pragma unroll
  for (int it = 0; it < 2; ++it) {         // 2048 floats = 512 float4
    int i = it * 256 + tid;
    if (i < 512) {
      float4 qP = ((const float4*)preP)[i];
      float4 qE = ((const float4*)preE)[i];
      w[0] += (double)qP.x + (double)qP.y + (double)qP.z + (double)qP.w;
      w[1] += (double)qE.x + (double)qE.y + (double)qE.z + (double)qE.w;
    }
  }
  block_reduce4_d(w, dbuf);
  double sumP = w[0], sumE = w[1];

  double me = (sum0 - sumE) / NN1;   // exact mean_offdiag 1/u
  float cf = (float)me;
  double z[4] = {0.0, 0.0, 0.0, 0.0};
  for (int i = tid; i < N_ROWS; i += 256) {
    float uii = __expf(-posl[i]);                 // 1 + d2_ii
    z[0] += (double)(1.0f / fmaf(cf, uii, 1.0f)); // sigmoid(pos_i), exact c
  }
  block_reduce4_d(z, dbuf);
  double sumSig = z[0];

  if (tid == 0) {
    double B = log(me);
    double mean_pos = sumP / (double)N_ROWS - B;
    double attraction = -mean_pos;
    double repulsion = me * exp(-B);                   // ~1.0
    double mean_neg = -(LN2 * sum1 + sumP) / NN1 - B;
    out8[0] = (float)(attraction + repulsion);
    out8[1] = (float)mean_pos;
    out8[2] = (float)mean_neg;
    out8[3] = (float)(sumSig / (double)N_ROWS);
    out8[4] = (float)((sumW - sumD) / NN1);
    out8[5] = (float)attraction;
    out8[6] = (float)repulsion;
    out8[7] = (float)B;
  }
}

// ---------------------------------------------------------------------------
extern "C" void kernel_launch(void* const* d_in, const int* in_sizes, int n_in,
                              void* d_out, int out_size, void* d_ws, size_t ws_size,
                              hipStream_t stream) {
  const float* x = (const float*)d_in[0];  // context_embedding
  const float* y = (const float*)d_in[1];  // target_embedding

  char* ws = (char*)d_ws;
  unsigned short* xb = (unsigned short*)ws;
  unsigned short* yb = (unsigned short*)(ws + (size_t)2 * 1024 * 1024);
  float* x2     = (float*)(ws + (size_t)4 * 1024 * 1024);
  float* y2     = x2 + N_ROWS;
  float* posl   = y2 + N_ROWS;
  float* parts0 = posl + N_ROWS;
  float* parts1 = parts0 + NBLK;
  float* partsW = parts1 + NBLK;
  float* partsD = partsW + NBLK;
  float* preP   = partsD + 64;
  float* preE   = preP + NPREP;

  hipLaunchKernelGGL(prep_kernel, dim3(NPREP), dim3(256), 0, stream,
                     x, y, xb, yb, x2, y2, posl, preP, preE);
  hipLaunchKernelGGL(gram_kernel, dim3(NBLK), dim3(512), 0, stream,
                     xb, yb, x2, y2, parts0, parts1, partsW, partsD);
  hipLaunchKernelGGL(fin_kernel, dim3(1), dim3(256), 0, stream,
                     parts0, parts1, partsW, partsD, preP, preE, posl,
                     (float*)d_out);
}

// Round 11
// 102.807 us; speedup vs baseline: 1.2494x; 1.1063x over previous
//
#include <hip/hip_runtime.h>

// LikelihoodRatioEstimator: N=8192, D=128 fp32 inputs, 8 fp32 scalar outputs.
//
// d2[i][j] = ||x_i||^2 + ||y_j||^2 - 2 x_i.y_j ; u = 1 + d2  (u in [~80,~500])
//   B = log(mean_offdiag(1/u));  mean_neg = -mean_offdiag(ln u) - B
//   mean_sig_neg = mean_offdiag(1/(1 + c*u)), c = exp(B)
//   pos path: diagonal only, exact fp32 (prep).
//
// Single gram pass: per-block cc = mean_tile(1/u) for the sigmoid sum (R6,
// absmax 0.0); diag blocks report their diag sigmoid terms for exact
// subtraction in fin; exact c from full sum(1/u) for everything else.
// 4-way rcp-combine + per-8 log-products in the epilogue (R10, absmax 0.0).
//
// R11: fp8(e4m3) gram. mfma_f32_16x16x32_fp8_fp8 (same shape/K as the bf16
// one, 8B operands): LDS tiles halve to 32KB/block -> 4 blocks/CU = 8
// waves/SIMD (2x R10's hiding); ds_read_b64 halves LDS-pipe time; FETCH
// halves. Error budget: e4m3-RNE dot err std ~1.2 abs on u~260, unbiased ->
// means over 67M pairs absorb it (2nd-order bias ~1e-5; tol 0.11). Diagonal
// (pos) path remains exact fp32. Epilogue/fin identical to R10.

#define N_ROWS 8192
#define DDIM 128
#define NBLK 4096           // (8192/128)^2
#define NPREP 2048
#define NN1 67100672.0      // 8192 * 8191
#define LN2 0.6931471805599453
#define TILE_INV (1.0f / 16384.0f)

typedef float f32x4 __attribute__((ext_vector_type(4)));

// ---------------------------------------------------------------------------
// prep: fp32 -> fp8(e4m3, RNE hw cvt), row norms (exact fp32), diagonal
// logits, and per-block partials of sum(posl) / sum(1/(1+d2_ii)).
__global__ __launch_bounds__(256) void prep_kernel(
    const float* __restrict__ x, const float* __restrict__ y,
    unsigned char* __restrict__ xb, unsigned char* __restrict__ yb,
    float* __restrict__ x2, float* __restrict__ y2, float* __restrict__ posl,
    float* __restrict__ preP, float* __restrict__ preE) {
  __shared__ float erP[4], erE[4];
  int tid = threadIdx.x;
  int wave = tid >> 6, lane = tid & 63;
  int r = blockIdx.x * 4 + wave;
  float2 xv = ((const float2*)(x + (size_t)r * DDIM))[lane];
  float2 yv = ((const float2*)(y + (size_t)r * DDIM))[lane];

  int px = __builtin_amdgcn_cvt_pk_fp8_f32(xv.x, xv.y, 0, false);
  int py = __builtin_amdgcn_cvt_pk_fp8_f32(yv.x, yv.y, 0, false);
  ((unsigned short*)xb)[(size_t)r * 64 + lane] = (unsigned short)px;
  ((unsigned short*)yb)[(size_t)r * 64 + lane] = (unsigned short)py;

  float xx = fmaf(xv.x, xv.x, xv.y * xv.y);
  float yy = fmaf(yv.x, yv.x, yv.y * yv.y);
  float xy = fmaf(xv.x, yv.x, xv.y * yv.y);
  #pragma unroll
  for (int o = 32; o; o >>= 1) {
    xx += __shfl_xor(xx, o);
    yy += __shfl_xor(yy, o);
    xy += __shfl_xor(xy, o);
  }
  if (lane == 0) {
    x2[r] = xx;
    y2[r] = yy;
    float d2 = fmaxf(xx + yy - 2.0f * xy, 0.0f);
    float pl = -__logf(1.0f + d2);
    posl[r] = pl;
    erP[wave] = pl;
    erE[wave] = 1.0f / (1.0f + d2);
  }
  __syncthreads();
  if (tid == 0) {
    preP[blockIdx.x] = erP[0] + erP[1] + erP[2] + erP[3];
    preE[blockIdx.x] = erE[0] + erE[1] + erE[2] + erE[3];
  }
}

// ---------------------------------------------------------------------------
// gram: 128x128 tile/block, 8 waves (2x4; 64x32 wave tiles), 4x2 fp8 MFMA
// frags. A+B in LDS with 8B-granular XOR swizzle (chunk ^ (row&15), 16
// chunks/row): frag ds_read_b64 conflict-free. Two-phase epilogue with
// 4-way rcp-combine and per-8 log-products (R10); u stored into acc.
__global__ __launch_bounds__(512, 2) void gram_kernel(
    const unsigned char* __restrict__ xb, const unsigned char* __restrict__ yb,
    const float* __restrict__ x2, const float* __restrict__ y2,
    float* __restrict__ parts0, float* __restrict__ parts1,
    float* __restrict__ partsW, float* __restrict__ partsD) {
  __shared__ long Asm[2048];    // 128 rows x 16 chunks x 8B = 16 KB
  __shared__ long Bsm[2048];    // 16 KB
  __shared__ float red[32];     // [0:8) s0, [8:16) s1, [16:24) sW, [24:32) sD

  int tid = threadIdx.x, bid = blockIdx.x;
  int tr = bid >> 6, tc = bid & 63;
  int wave = tid >> 6, lane = tid & 63;
  int wr = wave >> 2, wc = wave & 3;
  int quad = lane >> 4, m = lane & 15;

  const ulong2* Ag = (const ulong2*)xb + (size_t)tr * 1024;
  const ulong2* Bg = (const ulong2*)yb + (size_t)tc * 1024;
  #pragma unroll
  for (int it = 0; it < 2; ++it) {
    int cid = it * 512 + tid;          // [0,1024): row*8 + 16B-chunk
    int row = cid >> 3, c16 = cid & 7;
    int c8 = c16 * 2;
    int sw0 = row * 16 + (c8 ^ (row & 15));
    int sw1 = row * 16 + ((c8 + 1) ^ (row & 15));
    ulong2 va = Ag[cid];
    ulong2 vb = Bg[cid];
    Asm[sw0] = (long)va.x;
    Asm[sw1] = (long)va.y;
    Bsm[sw0] = (long)vb.x;
    Bsm[sw1] = (long)vb.y;
  }
  __syncthreads();

  int arow = wr * 64 + m;
  int brow = wc * 32 + m;

  f32x4 acc[4][2];
  #pragma unroll
  for (int i = 0; i < 4; ++i)
    #pragma unroll
    for (int j = 0; j < 2; ++j)
      acc[i][j] = (f32x4){0.f, 0.f, 0.f, 0.f};

  #pragma unroll
  for (int ks = 0; ks < 4; ++ks) {
    int ch = (ks * 4 + quad) ^ m;
    long af[4], bfv[2];
    #pragma unroll
    for (int f = 0; f < 4; ++f) af[f] = Asm[(arow + f * 16) * 16 + ch];
    #pragma unroll
    for (int f = 0; f < 2; ++f) bfv[f] = Bsm[(brow + f * 16) * 16 + ch];
    #pragma unroll
    for (int fi = 0; fi < 4; ++fi)
      #pragma unroll
      for (int fj = 0; fj < 2; ++fj)
        acc[fi][fj] = __builtin_amdgcn_mfma_f32_16x16x32_fp8_fp8(
            af[fi], bfv[fj], acc[fi][fj], 0, 0, 0);
  }

  // C/D layout: col = lane&15, row = quad*4 + reg. u >= ~75 -> no clamp.
  float x2v1[16], y2v[2];
  #pragma unroll
  for (int fi = 0; fi < 4; ++fi)
    #pragma unroll
    for (int r = 0; r < 4; ++r)
      x2v1[fi * 4 + r] =
          x2[tr * 128 + wr * 64 + fi * 16 + quad * 4 + r] + 1.0f;
  #pragma unroll
  for (int fj = 0; fj < 2; ++fj)
    y2v[fj] = y2[tc * 128 + wc * 32 + fj * 16 + m];

  // ---- phase A: sum 1/u via 4-way rcp-combine; one log2 per 8-elem prod.
  float s0a = 0.f, s0b = 0.f, s1 = 0.f;
  #pragma unroll
  for (int fi = 0; fi < 4; ++fi) {
    float pl;
    #pragma unroll
    for (int fj = 0; fj < 2; ++fj) {
      float u0 = fmaf(-2.0f, acc[fi][fj][0], x2v1[fi * 4 + 0] + y2v[fj]);
      float u1 = fmaf(-2.0f, acc[fi][fj][1], x2v1[fi * 4 + 1] + y2v[fj]);
      float u2 = fmaf(-2.0f, acc[fi][fj][2], x2v1[fi * 4 + 2] + y2v[fj]);
      float u3 = fmaf(-2.0f, acc[fi][fj][3], x2v1[fi * 4 + 3] + y2v[fj]);
      acc[fi][fj][0] = u0; acc[fi][fj][1] = u1;
      acc[fi][fj][2] = u2; acc[fi][fj][3] = u3;
      float P01 = u0 * u1, P23 = u2 * u3, P = P01 * P23;
      float rP = __builtin_amdgcn_rcpf(P);
      s0a = fmaf(rP * P23, u0 + u1, s0a);
      s0b = fmaf(rP * P01, u2 + u3, s0b);
      pl = (fj == 0) ? P : pl * P;      // fj unrolled: pl init'd at fj==0
    }
    s1 += __builtin_amdgcn_logf(pl);    // log2(prod of 8 u's <= ~2e21)
  }
  float s0 = s0a + s0b;
  #pragma unroll
  for (int o = 32; o; o >>= 1) {
    s0 += __shfl_xor(s0, o);
    s1 += __shfl_xor(s1, o);
  }
  if (lane == 0) { red[wave] = s0; red[8 + wave] = s1; }
  __syncthreads();
  float cc = 0.0f;
  #pragma unroll
  for (int w = 0; w < 8; ++w) cc += red[w];
  cc *= TILE_INV;                                // block-local mean(1/u)

  // ---- phase B: sum 1/(1+cc*u) via 4-way rcp-combine on v = 1+cc*u ----
  float sWa = 0.f, sWb = 0.f, sD = 0.f;
  bool isdiag = (tr == tc);
  if (!isdiag) {
    #pragma unroll
    for (int fi = 0; fi < 4; ++fi) {
      #pragma unroll
      for (int fj = 0; fj < 2; ++fj) {
        float v0 = fmaf(cc, acc[fi][fj][0], 1.0f);
        float v1 = fmaf(cc, acc[fi][fj][1], 1.0f);
        float v2 = fmaf(cc, acc[fi][fj][2], 1.0f);
        float v3 = fmaf(cc, acc[fi][fj][3], 1.0f);
        float Q01 = v0 * v1, Q23 = v2 * v3, Q = Q01 * Q23;
        float rQ = __builtin_amdgcn_rcpf(Q);
        sWa = fmaf(rQ * Q23, v0 + v1, sWa);
        sWb = fmaf(rQ * Q01, v2 + v3, sWb);
      }
    }
  } else {
    // 64 of 4096 blocks: per-element path to collect diag terms exactly.
    #pragma unroll
    for (int fi = 0; fi < 4; ++fi)
      #pragma unroll
      for (int fj = 0; fj < 2; ++fj)
        #pragma unroll
        for (int r = 0; r < 4; ++r) {
          float sg = __builtin_amdgcn_rcpf(fmaf(cc, acc[fi][fj][r], 1.0f));
          if (r & 1) sWa += sg; else sWb += sg;
          int lr = wr * 64 + fi * 16 + quad * 4 + r;
          int lc = wc * 32 + fj * 16 + m;
          sD += (lr == lc) ? sg : 0.0f;
        }
  }
  float sW = sWa + sWb;
  #pragma unroll
  for (int o = 32; o; o >>= 1) sW += __shfl_xor(sW, o);
  if (isdiag) {
    #pragma unroll
    for (int o = 32; o; o >>= 1) sD += __shfl_xor(sD, o);
    if (lane == 0) red[24 + wave] = sD;
  }
  if (lane == 0) red[16 + wave] = sW;
  __syncthreads();
  if (tid == 0) {
    float t0 = 0.f, t1 = 0.f, tW = 0.f;
    #pragma unroll
    for (int w = 0; w < 8; ++w) {
      t0 += red[w];
      t1 += red[8 + w];
      tW += red[16 + w];
    }
    parts0[bid] = t0;
    parts1[bid] = t1;
    partsW[bid] = tW;
    if (isdiag) {
      float tD = 0.f;
      #pragma unroll
      for (int w = 0; w < 8; ++w) tD += red[24 + w];
      partsD[tr] = tD;
    }
  }
}

// ---------------------------------------------------------------------------
// 4-wide packed double block reduction (one barrier tree for 4 sums).
__device__ __forceinline__ void block_reduce4_d(double* v, double* buf) {
  int tid = threadIdx.x;
  #pragma unroll
  for (int k = 0; k < 4; ++k) buf[k * 256 + tid] = v[k];
  __syncthreads();
  #pragma unroll
  for (int s = 128; s > 0; s >>= 1) {
    if (tid < s) {
      #pragma unroll
      for (int k = 0; k < 4; ++k) buf[k * 256 + tid] += buf[k * 256 + tid + s];
    }
    __syncthreads();
  }
  #pragma unroll
  for (int k = 0; k < 4; ++k) v[k] = buf[k * 256];
  __syncthreads();
}

// fin: all 8 outputs; double accumulation, float transcendentals. (R10)
__global__ __launch_bounds__(256) void fin_kernel(
    const float* __restrict__ parts0, const float* __restrict__ parts1,
    const float* __restrict__ partsW, const float* __restrict__ partsD,
    const float* __restrict__ preP, const float* __restrict__ preE,
    const float* __restrict__ posl, float* __restrict__ out8) {
  __shared__ double dbuf[1024];
  int tid = threadIdx.x;

  double v[4] = {0.0, 0.0, 0.0, 0.0};
  #pragma unroll
  for (int it = 0; it < 4; ++it) {         // 4096 floats = 1024 float4
    int i = it * 256 + tid;
    float4 q0 = ((const float4*)parts0)[i];
    float4 q1 = ((const float4*)parts1)[i];
    float4 qW = ((const float4*)partsW)[i];
    v[0] += (double)q0.x + (double)q0.y + (double)q0.z + (double)q0.w;
    v[1] += (double)q1.x + (double)q1.y + (double)q1.z + (double)q1.w;
    v[2] += (double)qW.x + (double)qW.y + (double)qW.z + (double)qW.w;
  }
  if (tid < 64) v[3] = (double)partsD[tid];   // diag sigmoid terms
  block_reduce4_d(v, dbuf);
  double sum0 = v[0], sum1 = v[1], sumW = v[2], sumD = v[3];

  double w[4] = {0.0, 0.0, 0.0, 0.0};
  if (tid < 512) {                         // 2048 floats = 512 float4
    float4 qP = ((const float4*)preP)[tid];
    float4 qE = ((const float4*)preE)[tid];
    w[0] += (double)qP.x + (double)qP.y + (double)qP.z + (double)qP.w;
    w[1] += (double)qE.x + (double)qE.y + (double)qE.z + (double)qE.w;
  }
  // 256 threads: cover remaining half explicitly
  {
    int i = 256 + tid;
    float4 qP = ((const float4*)preP)[i];
    float4 qE = ((const float4*)preE)[i];
    w[0] += (double)qP.x + (double)qP.y + (double)qP.z + (double)qP.w;
    w[1] += (double)qE.x + (double)qE.y + (double)qE.z + (double)qE.w;
  }
  block_reduce4_d(w, dbuf);
  double sumP = w[0], sumE = w[1];

  double me = (sum0 - sumE) / NN1;   // exact mean_offdiag 1/u
  float cf = (float)me;
  double z[4] = {0.0, 0.0, 0.0, 0.0};
  for (int i = tid; i < N_ROWS; i += 256) {
    float uii = __expf(-posl[i]);                 // 1 + d2_ii
    z[0] += (double)(1.0f / fmaf(cf, uii, 1.0f)); // sigmoid(pos_i), exact c
  }
  block_reduce4_d(z, dbuf);
  double sumSig = z[0];

  if (tid == 0) {
    double B = log(me);
    double mean_pos = sumP / (double)N_ROWS - B;
    double attraction = -mean_pos;
    double repulsion = me * exp(-B);                   // ~1.0
    double mean_neg = -(LN2 * sum1 + sumP) / NN1 - B;
    out8[0] = (float)(attraction + repulsion);
    out8[1] = (float)mean_pos;
    out8[2] = (float)mean_neg;
    out8[3] = (float)(sumSig / (double)N_ROWS);
    out8[4] = (float)((sumW - sumD) / NN1);
    out8[5] = (float)attraction;
    out8[6] = (float)repulsion;
    out8[7] = (float)B;
  }
}

// ---------------------------------------------------------------------------
extern "C" void kernel_launch(void* const* d_in, const int* in_sizes, int n_in,
                              void* d_out, int out_size, void* d_ws, size_t ws_size,
                              hipStream_t stream) {
  const float* x = (const float*)d_in[0];  // context_embedding
  const float* y = (const float*)d_in[1];  // target_embedding

  char* ws = (char*)d_ws;
  unsigned char* xb = (unsigned char*)ws;                       // 1 MB fp8
  unsigned char* yb = (unsigned char*)(ws + (size_t)1024 * 1024); // 1 MB fp8
  float* x2     = (float*)(ws + (size_t)2 * 1024 * 1024);
  float* y2     = x2 + N_ROWS;
  float* posl   = y2 + N_ROWS;
  float* parts0 = posl + N_ROWS;
  float* parts1 = parts0 + NBLK;
  float* partsW = parts1 + NBLK;
  float* partsD = partsW + NBLK;
  float* preP   = partsD + 64;
  float* preE   = preP + NPREP;

  hipLaunchKernelGGL(prep_kernel, dim3(NPREP), dim3(256), 0, stream,
                     x, y, xb, yb, x2, y2, posl, preP, preE);
  hipLaunchKernelGGL(gram_kernel, dim3(NBLK), dim3(512), 0, stream,
                     xb, yb, x2, y2, parts0, parts1, partsW, partsD);
  hipLaunchKernelGGL(fin_kernel, dim3(1), dim3(256), 0, stream,
                     parts0, parts1, partsW, partsD, preP, preE, posl,
                     (float*)d_out);
}